// Round 1
// baseline (2824.284 us; speedup 1.0000x reference)
//
#include <hip/hip_runtime.h>

// Autoregressive LSTM decoder, B=256, T=2048, IN=64, H=32, NCLS=5.
// One workgroup per batch row (256 blocks x 128 threads, 2 waves).
// Thread j owns gate row j (i:0-31, f:32-63, g:64-95, o:96-127).
// Serial chain per step: h -> gates -> (c,h) -> logits -> argmax -> P-select.
// prev-embedding contribution is precomputed per gate row into a 5-entry
// table P[m] (prev is always emb[argmax] or 0), removing the emb fetch and
// 64 FMAs from the serial path.

namespace {

constexpr int Tn  = 2048;
constexpr int INn = 64;
constexpr int Hn  = 32;
constexpr int Gn  = 128;
constexpr int NC  = 5;
constexpr int CH  = 32;          // steps per x-chunk
constexpr int CHF = CH * INn;    // floats per chunk = 2048 (8 KB)

__global__ __launch_bounds__(128, 1)
void ar_decode(const float* __restrict__ x,
               const float* __restrict__ W_ih,
               const float* __restrict__ W_hh,
               const float* __restrict__ b_ih,
               const float* __restrict__ b_hh,
               const float* __restrict__ W_fc,
               const float* __restrict__ b_fc,
               const float* __restrict__ emb,
               float* __restrict__ out)
{
    const int b   = blockIdx.x;
    const int j   = threadIdx.x;       // gate row
    const int typ = j >> 5;            // 0:i 1:f 2:g 3:o
    const int k   = j & (Hn - 1);

    __shared__ __align__(16) float s_x[2 * CHF];   // 16 KB x double buffer
    __shared__ float s_g[Gn];
    __shared__ float s_h[Hn];
    __shared__ int   s_m;

    // ---- static weights into registers ----
    float wih[INn];                    // x-half of W_ih row j
    #pragma unroll
    for (int i = 0; i < INn; ++i) wih[i] = W_ih[j * 2 * INn + i];
    float whh[Hn];
    #pragma unroll
    for (int q = 0; q < Hn; ++q) whh[q] = W_hh[j * Hn + q];
    const float bias = b_ih[j] + b_hh[j];

    // P[m] = dot(W_ih[j, 64:128], emb[m])
    float P0 = 0.f, P1 = 0.f, P2 = 0.f, P3 = 0.f, P4 = 0.f;
    #pragma unroll
    for (int i = 0; i < INn; ++i) {
        const float w = W_ih[j * 2 * INn + INn + i];
        P0 += w * emb[0 * INn + i];
        P1 += w * emb[1 * INn + i];
        P2 += w * emb[2 * INn + i];
        P3 += w * emb[3 * INn + i];
        P4 += w * emb[4 * INn + i];
    }

    // classifier weights: lane k holds W_fc[m][k] for the shuffle reduction
    const float wfc0 = W_fc[0 * Hn + k];
    const float wfc1 = W_fc[1 * Hn + k];
    const float wfc2 = W_fc[2 * Hn + k];
    const float wfc3 = W_fc[3 * Hn + k];
    const float wfc4 = W_fc[4 * Hn + k];
    const float bf0 = b_fc[0], bf1 = b_fc[1], bf2 = b_fc[2],
                bf3 = b_fc[3], bf4 = b_fc[4];

    const float* __restrict__ xb = x + (size_t)b * Tn * INn;
    float* __restrict__ ob = out + (size_t)b * Tn * NC;

    // ---- x prefetch: chunk 0 -> LDS buf0, chunk 1 -> registers ----
    float4 pf[4];                      // 64 B of next chunk per thread
    {
        const float4* src0 = (const float4*)(xb);
        #pragma unroll
        for (int r = 0; r < 4; ++r)
            ((float4*)s_x)[r * 128 + j] = src0[r * 128 + j];
        const float4* src1 = (const float4*)(xb + CHF);
        #pragma unroll
        for (int r = 0; r < 4; ++r) pf[r] = src1[r * 128 + j];
    }

    if (j < Hn) s_h[j] = 0.f;
    float c = 0.f;
    int m_prev = -1;                   // -1 => prev = 0 vector (t=0)
    __syncthreads();

    for (int t = 0; t < Tn; ++t) {
        const int q = t >> 5;          // chunk index
        if ((t & (CH - 1)) == 0 && t > 0) {
            // commit prefetched chunk q to LDS, start fetching chunk q+1
            float* dst = s_x + (q & 1) * CHF;
            #pragma unroll
            for (int r = 0; r < 4; ++r) ((float4*)dst)[r * 128 + j] = pf[r];
            __syncthreads();
            if (q + 1 < Tn / CH) {
                const float4* srcn = (const float4*)(xb + (size_t)(q + 1) * CHF);
                #pragma unroll
                for (int r = 0; r < 4; ++r) pf[r] = srcn[r * 128 + j];
            }
        }
        const float* __restrict__ xt = s_x + (q & 1) * CHF + (t & (CH - 1)) * INn;

        // ---- gate pre-activation ----
        float a0 = bias, a1 = 0.f, a2 = 0.f, a3 = 0.f;
        a0 += (m_prev == 0) ? P0 : (m_prev == 1) ? P1 : (m_prev == 2) ? P2
            : (m_prev == 3) ? P3 : (m_prev == 4) ? P4 : 0.f;
        #pragma unroll
        for (int i = 0; i < INn; i += 4) {
            a0 += wih[i + 0] * xt[i + 0];
            a1 += wih[i + 1] * xt[i + 1];
            a2 += wih[i + 2] * xt[i + 2];
            a3 += wih[i + 3] * xt[i + 3];
        }
        #pragma unroll
        for (int q2 = 0; q2 < Hn; q2 += 4) {
            a0 += whh[q2 + 0] * s_h[q2 + 0];
            a1 += whh[q2 + 1] * s_h[q2 + 1];
            a2 += whh[q2 + 2] * s_h[q2 + 2];
            a3 += whh[q2 + 3] * s_h[q2 + 3];
        }
        const float acc = (a0 + a1) + (a2 + a3);

        // activation: sigmoid for i,f,o; tanh(x) = 2*sigmoid(2x)-1 for g
        const float z   = (typ == 2) ? 2.f * acc : acc;
        const float sg  = 1.f / (1.f + __expf(-z));
        const float act = (typ == 2) ? 2.f * sg - 1.f : sg;

        s_g[j] = act;
        __syncthreads();               // B1: gates visible, h reads done

        // ---- wave0: c/h update, logits, softmax, argmax ----
        if (j < 64) {
            float hk = 0.f;
            if (j < Hn) {
                const float iv = s_g[k];
                const float fv = s_g[Hn + k];
                const float gv = s_g[2 * Hn + k];
                const float ov = s_g[3 * Hn + k];
                c = fv * c + iv * gv;
                const float e2 = __expf(2.f * c);
                const float th = 1.f - 2.f / (e2 + 1.f);
                hk = ov * th;
                s_h[k] = hk;
            }
            // logits via butterfly sum over lanes 0..31 (lanes 32..63 junk)
            float p0 = hk * wfc0, p1 = hk * wfc1, p2 = hk * wfc2,
                  p3 = hk * wfc3, p4 = hk * wfc4;
            #pragma unroll
            for (int d = 1; d < Hn; d <<= 1) {
                p0 += __shfl_xor(p0, d, 64);
                p1 += __shfl_xor(p1, d, 64);
                p2 += __shfl_xor(p2, d, 64);
                p3 += __shfl_xor(p3, d, 64);
                p4 += __shfl_xor(p4, d, 64);
            }
            p0 += bf0; p1 += bf1; p2 += bf2; p3 += bf3; p4 += bf4;
            // argmax, first-max-wins (matches np.argmax)
            int am = 0; float bv = p0;
            if (p1 > bv) { bv = p1; am = 1; }
            if (p2 > bv) { bv = p2; am = 2; }
            if (p3 > bv) { bv = p3; am = 3; }
            if (p4 > bv) { bv = p4; am = 4; }
            // log-softmax
            const float se = __expf(p0 - bv) + __expf(p1 - bv) + __expf(p2 - bv)
                           + __expf(p3 - bv) + __expf(p4 - bv);
            const float lse = bv + __logf(se);
            if (j < NC) {
                const float lp = ((j == 0) ? p0 : (j == 1) ? p1 : (j == 2) ? p2
                                : (j == 3) ? p3 : p4) - lse;
                ob[t * NC + j] = lp;
            }
            if (j == 0) s_m = am;
        }
        __syncthreads();               // B2: h(t+1) and argmax visible
        m_prev = __builtin_amdgcn_readfirstlane(s_m);
    }
}

} // namespace

extern "C" void kernel_launch(void* const* d_in, const int* in_sizes, int n_in,
                              void* d_out, int out_size, void* d_ws, size_t ws_size,
                              hipStream_t stream) {
    const float* x    = (const float*)d_in[0];
    // d_in[1] x_lengths (int64, all == T) unused
    // d_in[2] edge_list unused
    const float* W_ih = (const float*)d_in[3];
    const float* W_hh = (const float*)d_in[4];
    const float* b_ih = (const float*)d_in[5];
    const float* b_hh = (const float*)d_in[6];
    const float* W_fc = (const float*)d_in[7];
    const float* b_fc = (const float*)d_in[8];
    const float* emb  = (const float*)d_in[9];
    float* out = (float*)d_out;

    hipLaunchKernelGGL(ar_decode, dim3(256), dim3(128), 0, stream,
                       x, W_ih, W_hh, b_ih, b_hh, W_fc, b_fc, emb, out);
}

// Round 2
// 2470.798 us; speedup vs baseline: 1.1431x; 1.1431x over previous
//
#include <hip/hip_runtime.h>

// AR LSTM decoder, B=256, T=2048, IN=64, H=32, NCLS=5.
// ONE wave (64 lanes) per batch row: no barriers anywhere in the serial loop.
// Lane l: m = l>>1, par = l&1. Computes gate rows rA = par*32+m (i_m or f_m)
// and rB = 64+par*32+m (g_m or o_m), packed float2 over the K dimension so
// the compiler emits v_pk_fma_f32. Gate exchange via DPP quad_perm (xor 1).
// Logits via DPP row_shr/row_bcast wave reduction + readlane (no LDS).
// prev-embedding contribution precomputed into a per-lane 5-entry float2
// table (prev is always emb[argmax] or 0).

namespace {

typedef float f2 __attribute__((ext_vector_type(2)));
typedef unsigned int u32;
typedef const __attribute__((address_space(1))) u32* gas_ptr;
typedef __attribute__((address_space(3))) u32* las_ptr;

constexpr int Tn  = 2048;
constexpr int INn = 64;
constexpr int Hn  = 32;
constexpr int NC  = 5;
constexpr int CH  = 32;           // steps per x-chunk
constexpr int CHF = CH * INn;     // 2048 floats = 8 KB per chunk
constexpr int NCHUNK = Tn / CH;   // 64

__device__ __forceinline__ float rcpf(float x) { return __builtin_amdgcn_rcpf(x); }

template <int CTRL, int RM, int BM, bool BC>
__device__ __forceinline__ float dpp_add(float x) {
    int t = __builtin_amdgcn_update_dpp(0, __float_as_int(x), CTRL, RM, BM, BC);
    return x + __int_as_float(t);
}

// sum over all 64 lanes, result broadcast via readlane(63)
__device__ __forceinline__ float wave_sum64(float x) {
    x = dpp_add<0x111, 0xF, 0xF, true>(x);   // row_shr:1
    x = dpp_add<0x112, 0xF, 0xF, true>(x);   // row_shr:2
    x = dpp_add<0x114, 0xF, 0xF, true>(x);   // row_shr:4
    x = dpp_add<0x118, 0xF, 0xF, true>(x);   // row_shr:8  -> lane 15 of each row
    x = dpp_add<0x142, 0xA, 0xF, false>(x);  // row_bcast15 -> lanes 31,63
    x = dpp_add<0x143, 0xC, 0xF, false>(x);  // row_bcast31 -> lane 63 = total
    return __int_as_float(__builtin_amdgcn_readlane(__float_as_int(x), 63));
}

// swap with lane^1 (quad_perm 1,0,3,2)
__device__ __forceinline__ float dpp_swap1(float x) {
    int t = __builtin_amdgcn_update_dpp(0, __float_as_int(x), 0xB1, 0xF, 0xF, true);
    return __int_as_float(t);
}

// async global->LDS, 16B per lane: lds dest = base + lane*16
__device__ __forceinline__ void gl16(const float* g, float* l) {
    __builtin_amdgcn_global_load_lds((gas_ptr)g, (las_ptr)l, 16, 0, 0);
}

__global__ __launch_bounds__(64, 1)
void ar_decode(const float* __restrict__ x,
               const float* __restrict__ W_ih,
               const float* __restrict__ W_hh,
               const float* __restrict__ b_ih,
               const float* __restrict__ b_hh,
               const float* __restrict__ W_fc,
               const float* __restrict__ b_fc,
               const float* __restrict__ emb,
               float* __restrict__ out)
{
    const int b    = blockIdx.x;
    const int lane = threadIdx.x;      // 0..63
    const int m    = lane >> 1;        // hidden index 0..31
    const int par  = lane & 1;         // 0: rows (i_m, g_m)  1: rows (f_m, o_m)
    const bool even = (par == 0);
    const int rA = par * Hn + m;       // i-row or f-row
    const int rB = 2 * Hn + par * Hn + m; // g-row or o-row

    __shared__ __align__(16) float s_x[2 * CHF];  // 16 KB double buffer
    __shared__ __align__(16) float s_h[Hn];

    // ---- static weights into registers (packed over K) ----
    f2 wihA[INn / 2], wihB[INn / 2];
    {
        const f2* pA = (const f2*)(W_ih + rA * 2 * INn);
        const f2* pB = (const f2*)(W_ih + rB * 2 * INn);
        #pragma unroll
        for (int i = 0; i < INn / 2; ++i) { wihA[i] = pA[i]; wihB[i] = pB[i]; }
    }
    f2 whhA[Hn / 2], whhB[Hn / 2];
    {
        const f2* pA = (const f2*)(W_hh + rA * Hn);
        const f2* pB = (const f2*)(W_hh + rB * Hn);
        #pragma unroll
        for (int i = 0; i < Hn / 2; ++i) { whhA[i] = pA[i]; whhB[i] = pB[i]; }
    }
    const float biasA = b_ih[rA] + b_hh[rA];
    const float biasB = b_ih[rB] + b_hh[rB];

    // P[cls] = ( dot(W_ih[rA,64:128], emb[cls]), dot(W_ih[rB,64:128], emb[cls]) )
    f2 P[NC];
    #pragma unroll
    for (int cls = 0; cls < NC; ++cls) {
        float pa = 0.f, pb = 0.f;
        for (int i = 0; i < INn; ++i) {
            const float e = emb[cls * INn + i];
            pa += W_ih[rA * 2 * INn + INn + i] * e;
            pb += W_ih[rB * 2 * INn + INn + i] * e;
        }
        f2 v; v.x = pa; v.y = pb; P[cls] = v;
    }

    // classifier: lane holds 0.5*W_fc[cls][m] (h duplicated on both parities)
    const float wfc0 = 0.5f * W_fc[0 * Hn + m];
    const float wfc1 = 0.5f * W_fc[1 * Hn + m];
    const float wfc2 = 0.5f * W_fc[2 * Hn + m];
    const float wfc3 = 0.5f * W_fc[3 * Hn + m];
    const float wfc4 = 0.5f * W_fc[4 * Hn + m];
    const float bf0 = b_fc[0], bf1 = b_fc[1], bf2 = b_fc[2],
                bf3 = b_fc[3], bf4 = b_fc[4];

    // activation constants for row B: par==0 -> tanh(g): z*=2, act=2*sg-1
    const float zsB  = even ? 2.f : 1.f;
    const float mulB = even ? 2.f : 1.f;
    const float addB = even ? -1.f : 0.f;

    const float* __restrict__ xb = x + (size_t)b * Tn * INn;
    float* __restrict__ ob = out + (size_t)b * Tn * NC;

    // h = 0
    if (lane < Hn) s_h[lane] = 0.f;

    // prefetch chunks 0 and 1 (8 x 16B-per-lane each)
    #pragma unroll
    for (int r = 0; r < 8; ++r) gl16(xb + r * 256 + lane * 4, s_x + r * 256);
    #pragma unroll
    for (int r = 0; r < 8; ++r) gl16(xb + CHF + r * 256 + lane * 4, s_x + CHF + r * 256);
    asm volatile("s_waitcnt vmcnt(8)" ::: "memory");   // chunk 0 resident

    float c = 0.f;
    f2 Ps; Ps.x = 0.f; Ps.y = 0.f;    // prev-embedding contribution (t=0: zero)

    for (int q = 0; q < NCHUNK; ++q) {
        if (q > 0) {
            asm volatile("s_waitcnt vmcnt(0)" ::: "memory");  // chunk q resident
            if (q + 1 < NCHUNK) {
                const float* src = xb + (size_t)(q + 1) * CHF;
                float* dst = s_x + ((q + 1) & 1) * CHF;
                #pragma unroll
                for (int r = 0; r < 8; ++r) gl16(src + r * 256 + lane * 4, dst + r * 256);
            }
        }
        const f2* xchunk = (const f2*)(s_x + (q & 1) * CHF);

        #pragma unroll 2
        for (int s = 0; s < CH; ++s) {
            const f2* xt2 = xchunk + s * (INn / 2);

            // ---- gate pre-activations (packed, 4 chains per row) ----
            f2 aA0, aA1, aA2, aA3, aB0, aB1, aB2, aB3;
            aA0.x = biasA + Ps.x; aA0.y = 0.f;
            aB0.x = biasB + Ps.y; aB0.y = 0.f;
            aA1 = aA2 = aA3 = aB1 = aB2 = aB3 = (f2)(0.f);
            #pragma unroll
            for (int i = 0; i < INn / 2; i += 4) {
                const f2 x0 = xt2[i], x1 = xt2[i + 1], x2 = xt2[i + 2], x3 = xt2[i + 3];
                aA0 += wihA[i] * x0;     aB0 += wihB[i] * x0;
                aA1 += wihA[i + 1] * x1; aB1 += wihB[i + 1] * x1;
                aA2 += wihA[i + 2] * x2; aB2 += wihB[i + 2] * x2;
                aA3 += wihA[i + 3] * x3; aB3 += wihB[i + 3] * x3;
            }
            const f2* h2 = (const f2*)s_h;
            #pragma unroll
            for (int k2 = 0; k2 < Hn / 2; k2 += 4) {
                const f2 h0 = h2[k2], h1 = h2[k2 + 1], h3 = h2[k2 + 2], h4 = h2[k2 + 3];
                aA0 += whhA[k2] * h0;     aB0 += whhB[k2] * h0;
                aA1 += whhA[k2 + 1] * h1; aB1 += whhB[k2 + 1] * h1;
                aA2 += whhA[k2 + 2] * h3; aB2 += whhB[k2 + 2] * h3;
                aA3 += whhA[k2 + 3] * h4; aB3 += whhB[k2 + 3] * h4;
            }
            const f2 sA = (aA0 + aA1) + (aA2 + aA3);
            const f2 sB = (aB0 + aB1) + (aB2 + aB3);
            const float accA = sA.x + sA.y;
            const float accB = sB.x + sB.y;

            // ---- activations: A = sigmoid; B = tanh (par0) / sigmoid (par1)
            const float actA = rcpf(1.f + __expf(-accA));
            const float sgB  = rcpf(1.f + __expf(-zsB * accB));
            const float actB = fmaf(sgB, mulB, addB);

            // ---- exchange with partner lane (xor 1) via DPP ----
            const float qA = dpp_swap1(actA);
            const float qB = dpp_swap1(actB);
            const float iv = even ? actA : qA;
            const float fv = even ? qA : actA;
            const float gv = even ? actB : qB;
            const float ov = even ? qB : actB;

            // ---- cell update (both parities redundantly -> identical) ----
            c = fmaf(fv, c, iv * gv);
            const float e2 = __expf(2.f * c);
            const float th = 1.f - 2.f * rcpf(e2 + 1.f);
            const float h  = ov * th;
            if (even) s_h[m] = h;          // for next step's W_hh matvec

            // ---- logits: DPP wave reduction (h duplicated, wfc pre-halved)
            float p0 = wave_sum64(h * wfc0) + bf0;
            float p1 = wave_sum64(h * wfc1) + bf1;
            float p2 = wave_sum64(h * wfc2) + bf2;
            float p3 = wave_sum64(h * wfc3) + bf3;
            float p4 = wave_sum64(h * wfc4) + bf4;

            // ---- argmax (first-max-wins, matches np.argmax) ----
            int am = 0; float bv = p0;
            if (p1 > bv) { bv = p1; am = 1; }
            if (p2 > bv) { bv = p2; am = 2; }
            if (p3 > bv) { bv = p3; am = 3; }
            if (p4 > bv) { bv = p4; am = 4; }

            // ---- log-softmax + store (lanes 0..4, one wave-instruction) ----
            const float se = __expf(p0 - bv) + __expf(p1 - bv) + __expf(p2 - bv)
                           + __expf(p3 - bv) + __expf(p4 - bv);
            const float lse = bv + __logf(se);
            if (lane < NC) {
                const float pv = (lane == 0) ? p0 : (lane == 1) ? p1
                               : (lane == 2) ? p2 : (lane == 3) ? p3 : p4;
                ob[(size_t)(q * CH + s) * NC + lane] = pv - lse;
            }

            // ---- select prev-embedding contribution for next step ----
            Ps = (am == 0) ? P[0] : (am == 1) ? P[1] : (am == 2) ? P[2]
               : (am == 3) ? P[3] : P[4];
        }
    }
}

} // namespace

extern "C" void kernel_launch(void* const* d_in, const int* in_sizes, int n_in,
                              void* d_out, int out_size, void* d_ws, size_t ws_size,
                              hipStream_t stream) {
    const float* x    = (const float*)d_in[0];
    // d_in[1] x_lengths (all == T), d_in[2] edge_list: unused
    const float* W_ih = (const float*)d_in[3];
    const float* W_hh = (const float*)d_in[4];
    const float* b_ih = (const float*)d_in[5];
    const float* b_hh = (const float*)d_in[6];
    const float* W_fc = (const float*)d_in[7];
    const float* b_fc = (const float*)d_in[8];
    const float* emb  = (const float*)d_in[9];
    float* out = (float*)d_out;

    hipLaunchKernelGGL(ar_decode, dim3(256), dim3(64), 0, stream,
                       x, W_ih, W_hh, b_ih, b_hh, W_fc, b_fc, emb, out);
}

// Round 4
// 1446.022 us; speedup vs baseline: 1.9531x; 1.7087x over previous
//
#include <hip/hip_runtime.h>

// AR LSTM decoder, B=256, T=2048, IN=64, H=32, NCLS=5.
// 2 waves per block (1 block per batch row):
//   producer wave: gx[t] = W_ih[:, :64] @ x_t + bias for a 32-step chunk into
//     an LDS double buffer, one chunk ahead (acquire/release LDS flags, no
//     barriers). Holds the 128-VGPR wih weights (volatile-pinned so the
//     compiler cannot sink the loads into the loop — R2/R3 showed it does).
//   consumer wave: the serial recurrence. Lane l = 2m+par owns gate rows
//     rA = par*32+m (i/f) and rB = 64+par*32+m (g/o). Logits via the R2-proven
//     wave_sum64 DPP tree on the fresh in-register h (R3's bug: it used the
//     previous step's h).

namespace {

typedef float f2 __attribute__((ext_vector_type(2)));
typedef unsigned int u32;
typedef const __attribute__((address_space(1))) u32* gas_ptr;
typedef __attribute__((address_space(3))) u32* las_ptr;

constexpr int Tn  = 2048;
constexpr int INn = 64;
constexpr int Hn  = 32;
constexpr int NC  = 5;
constexpr int CH  = 32;            // steps per chunk
constexpr int CHF = CH * INn;      // 2048 floats x-chunk (8 KB)
constexpr int GXF = CH * 128;      // 4096 floats gx-chunk (16 KB)
constexpr int NCHUNK = Tn / CH;    // 64

__device__ __forceinline__ float rcpf(float x) { return __builtin_amdgcn_rcpf(x); }
__device__ __forceinline__ float hadd(f2 v) { return v.x + v.y; }

template <int CTRL, int RM, int BM, bool BC>
__device__ __forceinline__ float dpp_add(float x) {
    int t = __builtin_amdgcn_update_dpp(0, __float_as_int(x), CTRL, RM, BM, BC);
    return x + __int_as_float(t);
}

// sum over all 64 lanes, result broadcast via readlane(63)  [proven in R2]
__device__ __forceinline__ float wave_sum64(float x) {
    x = dpp_add<0x111, 0xF, 0xF, true>(x);   // row_shr:1
    x = dpp_add<0x112, 0xF, 0xF, true>(x);   // row_shr:2
    x = dpp_add<0x114, 0xF, 0xF, true>(x);   // row_shr:4
    x = dpp_add<0x118, 0xF, 0xF, true>(x);   // row_shr:8
    x = dpp_add<0x142, 0xA, 0xF, false>(x);  // row_bcast15
    x = dpp_add<0x143, 0xC, 0xF, false>(x);  // row_bcast31 -> lane 63 total
    return __int_as_float(__builtin_amdgcn_readlane(__float_as_int(x), 63));
}

__device__ __forceinline__ float dpp_swap1(float x) {   // quad_perm xor 1
    int t = __builtin_amdgcn_update_dpp(0, __float_as_int(x), 0xB1, 0xF, 0xF, true);
    return __int_as_float(t);
}

__device__ __forceinline__ void gl16(const float* g, float* l) {
    __builtin_amdgcn_global_load_lds((gas_ptr)g, (las_ptr)l, 16, 0, 0);
}

__device__ __forceinline__ int ld_acq(int* p) {
    return __hip_atomic_load(p, __ATOMIC_ACQUIRE, __HIP_MEMORY_SCOPE_WORKGROUP);
}
__device__ __forceinline__ void st_rel(int* p, int v) {
    __hip_atomic_store(p, v, __ATOMIC_RELEASE, __HIP_MEMORY_SCOPE_WORKGROUP);
}

__global__ __launch_bounds__(128, 1)
void ar_decode(const float* __restrict__ x,
               const float* __restrict__ W_ih,
               const float* __restrict__ W_hh,
               const float* __restrict__ b_ih,
               const float* __restrict__ b_hh,
               const float* __restrict__ W_fc,
               const float* __restrict__ b_fc,
               const float* __restrict__ emb,
               float* __restrict__ out)
{
    const int b    = blockIdx.x;
    const int tid  = threadIdx.x;
    const int lane = tid & 63;
    const int m    = lane >> 1;
    const int par  = lane & 1;
    const bool even = (par == 0);
    const int rA = par * Hn + m;            // i-row (par0) or f-row (par1)
    const int rB = 2 * Hn + par * Hn + m;   // g-row (par0) or o-row (par1)

    __shared__ __align__(16) float s_xp[2 * CHF];   // 16 KB x staging
    __shared__ __align__(16) float s_gx[2 * GXF];   // 32 KB gx double buffer
    __shared__ __align__(16) float s_h[Hn];
    __shared__ int s_prog;   // chunks produced
    __shared__ int s_cons;   // chunks consumed

    if (tid == 0) { s_prog = 0; s_cons = 0; }
    if (tid < Hn) s_h[tid] = 0.f;
    __syncthreads();

    const float* __restrict__ xb = x + (size_t)b * Tn * INn;

    if (tid >= 64) {
        // ===================== producer wave =====================
        f2 wA[INn / 2], wB[INn / 2];     // 128 VGPR — volatile-pinned loads
        {
            const volatile f2* pA = (const volatile f2*)(W_ih + (size_t)rA * 2 * INn);
            const volatile f2* pB = (const volatile f2*)(W_ih + (size_t)rB * 2 * INn);
            #pragma unroll
            for (int i = 0; i < INn / 2; ++i) { wA[i] = pA[i]; wB[i] = pB[i]; }
        }
        const float biasA = b_ih[rA] + b_hh[rA];
        const float biasB = b_ih[rB] + b_hh[rB];

        // prefetch x chunks 0,1
        #pragma unroll
        for (int r = 0; r < 8; ++r) gl16(xb + r * 256 + lane * 4, s_xp + r * 256);
        #pragma unroll
        for (int r = 0; r < 8; ++r) gl16(xb + CHF + r * 256 + lane * 4, s_xp + CHF + r * 256);

        for (int q = 0; q < NCHUNK; ++q) {
            if (q == NCHUNK - 1) asm volatile("s_waitcnt vmcnt(0)" ::: "memory");
            else                 asm volatile("s_waitcnt vmcnt(8)" ::: "memory");
            while (ld_acq(&s_cons) < q - 1) { }   // gx buf (q&1) free?

            const f2* xc  = (const f2*)(s_xp + (q & 1) * CHF);
            float*    gxd = s_gx + (q & 1) * GXF;
            #pragma unroll 2
            for (int s = 0; s < CH; ++s) {
                const f2* xt2 = xc + s * (INn / 2);
                f2 a0, a1, a2, a3, c0, c1, c2, c3;
                a0 = a1 = a2 = a3 = c0 = c1 = c2 = c3 = (f2)(0.f);
                #pragma unroll
                for (int i = 0; i < INn / 2; i += 4) {
                    const f2 x0 = xt2[i], x1 = xt2[i + 1], x2 = xt2[i + 2], x3 = xt2[i + 3];
                    a0 += wA[i] * x0;     c0 += wB[i] * x0;
                    a1 += wA[i + 1] * x1; c1 += wB[i + 1] * x1;
                    a2 += wA[i + 2] * x2; c2 += wB[i + 2] * x2;
                    a3 += wA[i + 3] * x3; c3 += wB[i + 3] * x3;
                }
                gxd[s * 128 + rA] = biasA + hadd((a0 + a1) + (a2 + a3));
                gxd[s * 128 + rB] = biasB + hadd((c0 + c1) + (c2 + c3));
            }
            if (lane == 0) st_rel(&s_prog, q + 1);   // release: gx drained first
            if (q + 2 < NCHUNK) {                    // refill the freed x buffer
                const float* src = xb + (size_t)(q + 2) * CHF;
                float* dst = s_xp + (q & 1) * CHF;
                #pragma unroll
                for (int r = 0; r < 8; ++r) gl16(src + r * 256 + lane * 4, dst + r * 256);
            }
        }
    } else {
        // ===================== consumer wave (serial chain) =====================
        f2 whA[Hn / 2], whB[Hn / 2];     // 64 VGPR — volatile-pinned loads
        {
            const volatile f2* pA = (const volatile f2*)(W_hh + (size_t)rA * Hn);
            const volatile f2* pB = (const volatile f2*)(W_hh + (size_t)rB * Hn);
            #pragma unroll
            for (int i = 0; i < Hn / 2; ++i) { whA[i] = pA[i]; whB[i] = pB[i]; }
        }

        // P[cls] = ( dot(W_ih[rA,64:128], emb[cls]), dot(W_ih[rB,64:128], emb[cls]) )
        f2 P[NC];
        #pragma unroll
        for (int cls = 0; cls < NC; ++cls) {
            float pa = 0.f, pb = 0.f;
            for (int i = 0; i < INn; ++i) {
                const float e = emb[cls * INn + i];
                pa += W_ih[(size_t)rA * 2 * INn + INn + i] * e;
                pb += W_ih[(size_t)rB * 2 * INn + INn + i] * e;
            }
            f2 v; v.x = pa; v.y = pb; P[cls] = v;
        }

        // classifier: lane holds 0.5*W_fc[cls][m] (h duplicated on parities)
        const float wfc0 = 0.5f * W_fc[0 * Hn + m];
        const float wfc1 = 0.5f * W_fc[1 * Hn + m];
        const float wfc2 = 0.5f * W_fc[2 * Hn + m];
        const float wfc3 = 0.5f * W_fc[3 * Hn + m];
        const float wfc4 = 0.5f * W_fc[4 * Hn + m];
        const float bf0 = b_fc[0], bf1 = b_fc[1], bf2 = b_fc[2],
                    bf3 = b_fc[3], bf4 = b_fc[4];

        const float zsB  = even ? 2.f : 1.f;   // g: tanh(z) = 2*sig(2z)-1
        const float mulB = even ? 2.f : 1.f;
        const float addB = even ? -1.f : 0.f;

        float* __restrict__ ob = out + (size_t)b * Tn * NC;

        float c = 0.f;
        f2 Ps; Ps.x = 0.f; Ps.y = 0.f;

        for (int q = 0; q < NCHUNK; ++q) {
            while (ld_acq(&s_prog) < q + 1) { }      // wait for gx chunk q
            const float* gxc = s_gx + (q & 1) * GXF;

            #pragma unroll 2
            for (int s = 0; s < CH; ++s) {
                // gate inputs from producer (off the h-chain)
                const float gA = gxc[s * 128 + rA];
                const float gB = gxc[s * 128 + rB];

                // h broadcast from LDS (previous step's h)
                const f2* h2 = (const f2*)s_h;
                f2 hv[Hn / 2];
                #pragma unroll
                for (int i = 0; i < Hn / 2; ++i) hv[i] = h2[i];

                // W_hh · h (4 chains per row)
                f2 aA0, aA1, aA2, aA3, aB0, aB1, aB2, aB3;
                aA0 = aA1 = aA2 = aA3 = aB0 = aB1 = aB2 = aB3 = (f2)(0.f);
                #pragma unroll
                for (int i = 0; i < Hn / 2; i += 4) {
                    const f2 h0 = hv[i], h1 = hv[i + 1], h3 = hv[i + 2], h4 = hv[i + 3];
                    aA0 += whA[i] * h0;     aB0 += whB[i] * h0;
                    aA1 += whA[i + 1] * h1; aB1 += whB[i + 1] * h1;
                    aA2 += whA[i + 2] * h3; aB2 += whB[i + 2] * h3;
                    aA3 += whA[i + 3] * h4; aB3 += whB[i + 3] * h4;
                }
                const float accA = gA + hadd((aA0 + aA1) + (aA2 + aA3)) + Ps.x;
                const float accB = gB + hadd((aB0 + aB1) + (aB2 + aB3)) + Ps.y;

                // activations: A = sigmoid (i/f); B = tanh (g) / sigmoid (o)
                const float actA = rcpf(1.f + __expf(-accA));
                const float sgB  = rcpf(1.f + __expf(-zsB * accB));
                const float actB = fmaf(sgB, mulB, addB);

                // pair exchange (xor 1)
                const float qA = dpp_swap1(actA);
                const float qB = dpp_swap1(actB);
                const float iv = even ? actA : qA;
                const float fv = even ? qA : actA;
                const float gv = even ? actB : qB;
                const float ov = even ? qB : actB;

                // cell update (redundant in both parities -> identical)
                c = fmaf(fv, c, iv * gv);
                const float e2 = __expf(2.f * c);
                const float th = 1.f - 2.f * rcpf(e2 + 1.f);
                const float h  = ov * th;
                if (even) s_h[m] = h;     // for next step's matvec (off-chain here)

                // logits from the FRESH in-register h (R3's bug fixed)
                float p0 = wave_sum64(h * wfc0) + bf0;
                float p1 = wave_sum64(h * wfc1) + bf1;
                float p2 = wave_sum64(h * wfc2) + bf2;
                float p3 = wave_sum64(h * wfc3) + bf3;
                float p4 = wave_sum64(h * wfc4) + bf4;

                // argmax (first-max-wins, matches np.argmax)
                int am = 0; float bv = p0;
                if (p1 > bv) { bv = p1; am = 1; }
                if (p2 > bv) { bv = p2; am = 2; }
                if (p3 > bv) { bv = p3; am = 3; }
                if (p4 > bv) { bv = p4; am = 4; }

                // next-step prev-embedding contribution
                Ps = (am == 0) ? P[0] : (am == 1) ? P[1] : (am == 2) ? P[2]
                   : (am == 3) ? P[3] : P[4];

                // log-softmax + store (off-chain)
                const float se = __expf(p0 - bv) + __expf(p1 - bv) + __expf(p2 - bv)
                               + __expf(p3 - bv) + __expf(p4 - bv);
                const float lse = bv + __logf(se);
                if (lane < NC) {
                    float pv = p0;
                    pv = (lane == 1) ? p1 : pv;
                    pv = (lane == 2) ? p2 : pv;
                    pv = (lane == 3) ? p3 : pv;
                    pv = (lane == 4) ? p4 : pv;
                    ob[(size_t)(q * CH + s) * NC + lane] = pv - lse;
                }
            }
            if (lane == 0) st_rel(&s_cons, q + 1);   // gx buf (q&1) free
        }
    }
}

} // namespace

extern "C" void kernel_launch(void* const* d_in, const int* in_sizes, int n_in,
                              void* d_out, int out_size, void* d_ws, size_t ws_size,
                              hipStream_t stream) {
    (void)in_sizes; (void)n_in; (void)d_ws; (void)ws_size; (void)out_size;
    const float* x    = (const float*)d_in[0];
    // d_in[1] x_lengths (all == T), d_in[2] edge_list: unused
    const float* W_ih = (const float*)d_in[3];
    const float* W_hh = (const float*)d_in[4];
    const float* b_ih = (const float*)d_in[5];
    const float* b_hh = (const float*)d_in[6];
    const float* W_fc = (const float*)d_in[7];
    const float* b_fc = (const float*)d_in[8];
    const float* emb  = (const float*)d_in[9];
    float* out = (float*)d_out;

    hipLaunchKernelGGL(ar_decode, dim3(256), dim3(128), 0, stream,
                       x, W_ih, W_hh, b_ih, b_hh, W_fc, b_fc, emb, out);
}